// Round 8
// baseline (309.809 us; speedup 1.0000x reference)
//
#include <hip/hip_runtime.h>
#include <stdint.h>

#define B_ 4
#define N_ 2048
#define T_ 8
#define NL_ 64
#define DIM_ 1024
#define H_ 16
#define HD_ 64
#define TN_ (T_*NL_)   // 512

typedef __bf16 bf16x8 __attribute__((ext_vector_type(8)));
typedef float f32x4 __attribute__((ext_vector_type(4)));

__device__ __forceinline__ float b2f(unsigned short x) {
  union { uint32_t u; float f; } v; v.u = ((uint32_t)x) << 16; return v.f;
}
__device__ __forceinline__ unsigned short f2b(float f) {
  union { float f; uint32_t u; } v; v.f = f;
  uint32_t r = v.u + 0x7FFFu + ((v.u >> 16) & 1u);
  return (unsigned short)(r >> 16);
}

// ---------------- fp32-vs-bf16 storage detection ----------------
__global__ void detect_kernel(const unsigned short* __restrict__ text, int* __restrict__ flag) {
  int t = threadIdx.x;
  int bad = 0;
  #pragma unroll
  for (int i = 0; i < 16; i++) {
    unsigned short w = text[t * 16 + i];
    int e = (w >> 7) & 0xFF;
    if (e != 0 && (e < 90 || e > 150)) bad++;
  }
  __shared__ int red[256];
  red[t] = bad;
  __syncthreads();
  for (int o = 128; o > 0; o >>= 1) { if (t < o) red[t] += red[t + o]; __syncthreads(); }
  if (t == 0) flag[0] = (red[0] > 256) ? 1 : 0;   // 1 = fp32 storage
}

// ---------------- merged cast to bf16: media (2M elems) + bo (1K elems) --------
__global__ void cast2_kernel(const void* __restrict__ media, unsigned short* __restrict__ mb,
                             const void* __restrict__ bo, unsigned short* __restrict__ bob,
                             const int* __restrict__ flag) {
  const int N4M = (B_*T_*NL_*DIM_) / 4;   // 524288
  int i = blockIdx.x * 256 + threadIdx.x;
  bool isf = (*flag != 0);
  if (i < N4M) {
    ushort4 o;
    if (isf) {
      float4 v = ((const float4*)media)[i];
      o.x = f2b(v.x); o.y = f2b(v.y); o.z = f2b(v.z); o.w = f2b(v.w);
    } else {
      o = ((const ushort4*)media)[i];
    }
    ((ushort4*)mb)[i] = o;
  } else {
    int j = i - N4M;
    if (j < DIM_/4) {
      ushort4 o;
      if (isf) {
        float4 v = ((const float4*)bo)[j];
        o.x = f2b(v.x); o.y = f2b(v.y); o.z = f2b(v.z); o.w = f2b(v.w);
      } else {
        o = ((const ushort4*)bo)[j];
      }
      ((ushort4*)bob)[j] = o;
    }
  }
}

// ---------------- text_times: detect storage (bool-bytes vs int32) + block scan ----
__global__ void times_kernel(const void* __restrict__ locs, int* __restrict__ tt) {
  int b = blockIdx.x, t = threadIdx.x;
  const unsigned char* p8 = (const unsigned char*)locs;
  const int* p32 = (const int*)locs;
  __shared__ int red[256];
  int cnt = 0;
  for (int i = t; i < B_*N_; i += 256) cnt += (p8[i] != 0) ? 1 : 0;
  red[t] = cnt;
  __syncthreads();
  for (int off = 128; off > 0; off >>= 1) {
    if (t < off) red[t] += red[t + off];
    __syncthreads();
  }
  int total = red[0];
  __syncthreads();
  bool isb = (total >= 2 * T_);
  int x[8];
  int base = b * N_ + t * 8;
  if (isb) {
    #pragma unroll
    for (int i = 0; i < 8; i++) x[i] = (int)(p8[base + i] != 0);
  } else {
    #pragma unroll
    for (int i = 0; i < 8; i++) x[i] = (int)(p32[base + i] != 0);
  }
  #pragma unroll
  for (int i = 1; i < 8; i++) x[i] += x[i-1];
  int tot = x[7];
  red[t] = tot;
  __syncthreads();
  for (int off = 1; off < 256; off <<= 1) {
    int v = (t >= off) ? red[t - off] : 0;
    __syncthreads();
    red[t] += v;
    __syncthreads();
  }
  int excl = red[t] - tot;
  #pragma unroll
  for (int i = 0; i < 8; i++) tt[base + i] = excl + x[i];
}

// ---------------- LayerNorm (row per block), dtype-flag aware ----------------
__global__ void ln_kernel(const void* __restrict__ x,
                          const void* __restrict__ g,
                          const void* __restrict__ bta,
                          unsigned short* __restrict__ y,
                          const int* __restrict__ flag) {
  int row = blockIdx.x;
  int t = threadIdx.x;
  bool isf = (*flag != 0);
  float f0, f1, f2, f3, g0, g1, g2, g3, c0, c1, c2, c3;
  if (isf) {
    float4 xv = ((const float4*)x)[(size_t)row * (DIM_/4) + t];
    f0 = xv.x; f1 = xv.y; f2 = xv.z; f3 = xv.w;
    float4 gv = ((const float4*)g)[t];
    g0 = gv.x; g1 = gv.y; g2 = gv.z; g3 = gv.w;
    float4 bv = ((const float4*)bta)[t];
    c0 = bv.x; c1 = bv.y; c2 = bv.z; c3 = bv.w;
  } else {
    ushort4 xv = ((const ushort4*)x)[(size_t)row * (DIM_/4) + t];
    f0 = b2f(xv.x); f1 = b2f(xv.y); f2 = b2f(xv.z); f3 = b2f(xv.w);
    ushort4 gv = ((const ushort4*)g)[t];
    g0 = b2f(gv.x); g1 = b2f(gv.y); g2 = b2f(gv.z); g3 = b2f(gv.w);
    ushort4 bv = ((const ushort4*)bta)[t];
    c0 = b2f(bv.x); c1 = b2f(bv.y); c2 = b2f(bv.z); c3 = b2f(bv.w);
  }
  float s  = f0 + f1 + f2 + f3;
  float s2 = f0*f0 + f1*f1 + f2*f2 + f3*f3;
  for (int off = 32; off > 0; off >>= 1) { s += __shfl_xor(s, off); s2 += __shfl_xor(s2, off); }
  __shared__ float sm[8];
  int wave = t >> 6, lane = t & 63;
  if (lane == 0) { sm[wave] = s; sm[wave + 4] = s2; }
  __syncthreads();
  float ts  = sm[0] + sm[1] + sm[2] + sm[3];
  float ts2 = sm[4] + sm[5] + sm[6] + sm[7];
  float mean = ts * (1.0f / DIM_);
  float var  = ts2 * (1.0f / DIM_) - mean * mean;
  float rs = rsqrtf(var + 1e-5f);
  ushort4 o;
  o.x = f2b((f0 - mean) * rs * g0 + c0);
  o.y = f2b((f1 - mean) * rs * g1 + c1);
  o.z = f2b((f2 - mean) * rs * g2 + c2);
  o.w = f2b((f3 - mean) * rs * g3 + c3);
  ((ushort4*)(y + (size_t)row * DIM_))[t] = o;
}

// ---------------- merged transpose+cast of all 3 weights (grid.z selects) ------
__global__ void transpose3_kernel(const void* __restrict__ wq, unsigned short* __restrict__ wqt,
                                  const void* __restrict__ wkv, unsigned short* __restrict__ wkvt,
                                  const void* __restrict__ wo, unsigned short* __restrict__ wot,
                                  const int* __restrict__ flag) {
  const void* src; unsigned short* dst; int C;
  if (blockIdx.z == 0)      { src = wq;  dst = wqt;  C = 1024; }
  else if (blockIdx.z == 1) { src = wkv; dst = wkvt; C = 2048; }
  else                      { src = wo;  dst = wot;  C = 1024; }
  const int R = 1024;
  int bx = blockIdx.x * 32, by = blockIdx.y * 32;
  if (bx >= C) return;
  __shared__ unsigned short tile[32][33];
  int x = threadIdx.x, y = threadIdx.y;
  if (*flag) {
    const float* s = (const float*)src;
    for (int i = y; i < 32; i += 8) tile[i][x] = f2b(s[(size_t)(by + i) * C + bx + x]);
  } else {
    const unsigned short* s = (const unsigned short*)src;
    for (int i = y; i < 32; i += 8) tile[i][x] = s[(size_t)(by + i) * C + bx + x];
  }
  __syncthreads();
  for (int i = y; i < 32; i += 8) dst[(size_t)(bx + i) * R + by + x] = tile[x][i];
}

// ---------------- register-fragment 64x64 GEMM core (no LDS, no barriers) -------
// C[M,N] = A[M,K] @ Bt[N,K]^T. One wave per 64x64 tile. Fragments load straight
// from global (L1/L2) into VGPRs, ping-pong double-buffered so the next kstep's
// loads are in flight during the current kstep's 16 MFMAs.
// Block mapping is m-major: blocks sharing an A row-tile sit 8 apart -> same XCD
// (bid%8 round-robin heuristic) -> A fetched from HBM once per XCD.
#define MFMA16(av, bv)                                                            \
  {                                                                               \
    _Pragma("unroll")                                                             \
    for (int i = 0; i < 4; i++)                                                   \
      _Pragma("unroll")                                                           \
      for (int j = 0; j < 4; j++)                                                 \
        acc[i][j] = __builtin_amdgcn_mfma_f32_16x16x32_bf16(av[i], bv[j], acc[i][j], 0, 0, 0); \
  }

__device__ __forceinline__ void gemm_core(const unsigned short* __restrict__ A,
                                          const unsigned short* __restrict__ Bt,
                                          unsigned short* __restrict__ C,
                                          float* __restrict__ Cf,
                                          const unsigned short* __restrict__ bias,
                                          int bid, int M, int N, int K,
                                          bool f32o, int lane) {
  int mBlks = M >> 6;
  int m0 = (bid % mBlks) * 64;
  int n0 = (bid / mBlks) * 64;
  int lr = lane & 15, g8 = (lane >> 4) * 8;
  const unsigned short* ap = A  + (size_t)(m0 + lr) * K + g8;
  const unsigned short* bp = Bt + (size_t)(n0 + lr) * K + g8;
  const size_t rs = (size_t)16 * K;    // 16-row stride in elements

  f32x4 acc[4][4];
  #pragma unroll
  for (int i = 0; i < 4; i++)
    #pragma unroll
    for (int j = 0; j < 4; j++)
      #pragma unroll
      for (int r = 0; r < 4; r++) acc[i][j][r] = 0.f;

  bf16x8 a0[4], b0[4], a1[4], b1[4];
  #pragma unroll
  for (int i = 0; i < 4; i++) {
    a0[i] = *(const bf16x8*)(ap + i * rs);
    b0[i] = *(const bf16x8*)(bp + i * rs);
  }
  int k = 0;
  for (; k + 64 < K; k += 64) {
    #pragma unroll
    for (int i = 0; i < 4; i++) {
      a1[i] = *(const bf16x8*)(ap + i * rs + k + 32);
      b1[i] = *(const bf16x8*)(bp + i * rs + k + 32);
    }
    MFMA16(a0, b0);
    #pragma unroll
    for (int i = 0; i < 4; i++) {
      a0[i] = *(const bf16x8*)(ap + i * rs + k + 64);
      b0[i] = *(const bf16x8*)(bp + i * rs + k + 64);
    }
    MFMA16(a1, b1);
  }
  { // tail 64 (k = K-64)
    #pragma unroll
    for (int i = 0; i < 4; i++) {
      a1[i] = *(const bf16x8*)(ap + i * rs + k + 32);
      b1[i] = *(const bf16x8*)(bp + i * rs + k + 32);
    }
    MFMA16(a0, b0);
    MFMA16(a1, b1);
  }

  int rbase = (lane >> 4) * 4;
  #pragma unroll
  for (int i = 0; i < 4; i++) {
    #pragma unroll
    for (int j = 0; j < 4; j++) {
      int row = m0 + i * 16 + rbase;
      int col = n0 + j * 16 + lr;
      float bv = bias ? b2f(bias[col]) : 0.f;
      if (f32o) {
        #pragma unroll
        for (int r = 0; r < 4; r++)
          Cf[(size_t)(row + r) * N + col] = acc[i][j][r] + bv;
      } else {
        #pragma unroll
        for (int r = 0; r < 4; r++)
          C[(size_t)(row + r) * N + col] = f2b(acc[i][j][r] + bv);
      }
    }
  }
}

// fused q-GEMM (blocks [0,2048)) + kv-GEMM (blocks [2048,3072)) -> 12 waves/CU
__global__ __launch_bounds__(64) void gemm_qkv(const unsigned short* __restrict__ tn,
                                               const unsigned short* __restrict__ wqt,
                                               unsigned short* __restrict__ qb,
                                               const unsigned short* __restrict__ mb,
                                               const unsigned short* __restrict__ wkvt,
                                               unsigned short* __restrict__ kvb) {
  int bid = blockIdx.x;
  int lane = threadIdx.x;
  if (bid < 2048)
    gemm_core(tn, wqt, qb, nullptr, nullptr, bid, B_ * N_, DIM_, DIM_, false, lane);
  else
    gemm_core(mb, wkvt, kvb, nullptr, nullptr, bid - 2048, B_ * TN_, 2 * DIM_, DIM_, false, lane);
}

__global__ __launch_bounds__(64) void gemm_out(const unsigned short* __restrict__ ao,
                                               const unsigned short* __restrict__ wot,
                                               unsigned short* __restrict__ C,
                                               float* __restrict__ Cf,
                                               const unsigned short* __restrict__ bias,
                                               const int* __restrict__ flag) {
  bool f32o = (*flag != 0);
  gemm_core(ao, wot, C, Cf, bias, blockIdx.x, B_ * N_, DIM_, DIM_, f32o, threadIdx.x);
}

// ---------------- MFMA attention: 1 wave per (b, 64-row tile, head) -------------
__global__ __launch_bounds__(64) void attn_mfma(const unsigned short* __restrict__ q,
                                                const unsigned short* __restrict__ kv,
                                                const int* __restrict__ tt,
                                                unsigned short* __restrict__ ao) {
  __shared__ unsigned short Vt[64][72];   // V^T [d][key]
  __shared__ unsigned short Ps[64][72];   // P [q][key]; reused as O staging
  int bid = blockIdx.x;
  int h  = bid & 15;
  int nt = (bid >> 4) & 31;
  int b  = bid >> 9;
  int bn0 = b * N_ + nt * 64;
  int lane = threadIdx.x & 63;
  int lr = lane & 15;
  int g  = lane >> 4;
  int g8 = g * 8;

  int tv = tt[bn0];             // tile-uniform by mask structure
  float vmul = (tv >= 1 && tv <= T_) ? 1.f : 0.f;
  int tvc = tv < 1 ? 1 : (tv > T_ ? T_ : tv);
  int kvrow0 = b * TN_ + (tvc - 1) * NL_;

  const unsigned short* vbase = kv + (size_t)kvrow0 * (2 * DIM_) + DIM_ + h * HD_;
  #pragma unroll
  for (int d0 = 0; d0 < 64; d0 += 8) {
    uint4 v = *(const uint4*)(vbase + (size_t)lane * (2 * DIM_) + d0);
    Vt[d0 + 0][lane] = (unsigned short)(v.x & 0xffff);
    Vt[d0 + 1][lane] = (unsigned short)(v.x >> 16);
    Vt[d0 + 2][lane] = (unsigned short)(v.y & 0xffff);
    Vt[d0 + 3][lane] = (unsigned short)(v.y >> 16);
    Vt[d0 + 4][lane] = (unsigned short)(v.z & 0xffff);
    Vt[d0 + 5][lane] = (unsigned short)(v.z >> 16);
    Vt[d0 + 6][lane] = (unsigned short)(v.w & 0xffff);
    Vt[d0 + 7][lane] = (unsigned short)(v.w >> 16);
  }

  f32x4 S[4][4];
  #pragma unroll
  for (int i = 0; i < 4; i++)
    #pragma unroll
    for (int j = 0; j < 4; j++)
      #pragma unroll
      for (int r = 0; r < 4; r++) S[i][j][r] = 0.f;
  #pragma unroll
  for (int ks = 0; ks < 2; ks++) {
    bf16x8 aQ[4], bK[4];
    #pragma unroll
    for (int mi = 0; mi < 4; mi++)
      aQ[mi] = *(const bf16x8*)(q + (size_t)(bn0 + mi * 16 + lr) * DIM_ + h * HD_ + ks * 32 + g8);
    #pragma unroll
    for (int ni = 0; ni < 4; ni++)
      bK[ni] = *(const bf16x8*)(kv + (size_t)(kvrow0 + ni * 16 + lr) * (2 * DIM_) + h * HD_ + ks * 32 + g8);
    #pragma unroll
    for (int mi = 0; mi < 4; mi++)
      #pragma unroll
      for (int ni = 0; ni < 4; ni++)
        S[mi][ni] = __builtin_amdgcn_mfma_f32_16x16x32_bf16(aQ[mi], bK[ni], S[mi][ni], 0, 0, 0);
  }

  #pragma unroll
  for (int mi = 0; mi < 4; mi++) {
    #pragma unroll
    for (int r = 0; r < 4; r++) {
      float mx = fmaxf(fmaxf(S[mi][0][r], S[mi][1][r]), fmaxf(S[mi][2][r], S[mi][3][r]));
      mx = fmaxf(mx, __shfl_xor(mx, 1));
      mx = fmaxf(mx, __shfl_xor(mx, 2));
      mx = fmaxf(mx, __shfl_xor(mx, 4));
      mx = fmaxf(mx, __shfl_xor(mx, 8));
      float e0 = __expf(S[mi][0][r] - mx);
      float e1 = __expf(S[mi][1][r] - mx);
      float e2 = __expf(S[mi][2][r] - mx);
      float e3 = __expf(S[mi][3][r] - mx);
      float sum = e0 + e1 + e2 + e3;
      sum += __shfl_xor(sum, 1);
      sum += __shfl_xor(sum, 2);
      sum += __shfl_xor(sum, 4);
      sum += __shfl_xor(sum, 8);
      float inv = 1.f / sum;
      int qrow = mi * 16 + g * 4 + r;
      Ps[qrow][ 0 + lr] = f2b(e0 * inv);
      Ps[qrow][16 + lr] = f2b(e1 * inv);
      Ps[qrow][32 + lr] = f2b(e2 * inv);
      Ps[qrow][48 + lr] = f2b(e3 * inv);
    }
  }
  __syncthreads();

  f32x4 O[4][4];
  #pragma unroll
  for (int i = 0; i < 4; i++)
    #pragma unroll
    for (int j = 0; j < 4; j++)
      #pragma unroll
      for (int r = 0; r < 4; r++) O[i][j][r] = 0.f;
  #pragma unroll
  for (int ks = 0; ks < 2; ks++) {
    bf16x8 aP[4], bV[4];
    #pragma unroll
    for (int mi = 0; mi < 4; mi++)
      aP[mi] = *(const bf16x8*)(&Ps[mi * 16 + lr][ks * 32 + g8]);
    #pragma unroll
    for (int ni = 0; ni < 4; ni++)
      bV[ni] = *(const bf16x8*)(&Vt[ni * 16 + lr][ks * 32 + g8]);
    #pragma unroll
    for (int mi = 0; mi < 4; mi++)
      #pragma unroll
      for (int ni = 0; ni < 4; ni++)
        O[mi][ni] = __builtin_amdgcn_mfma_f32_16x16x32_bf16(aP[mi], bV[ni], O[mi][ni], 0, 0, 0);
  }
  __syncthreads();

  #pragma unroll
  for (int mi = 0; mi < 4; mi++)
    #pragma unroll
    for (int ni = 0; ni < 4; ni++)
      #pragma unroll
      for (int r = 0; r < 4; r++)
        Ps[mi * 16 + g * 4 + r][ni * 16 + lr] = f2b(O[mi][ni][r] * vmul);
  __syncthreads();
  uint4* dst = (uint4*)(ao + (size_t)(bn0 + lane) * DIM_ + h * HD_);
  #pragma unroll
  for (int c = 0; c < 8; c++)
    dst[c] = *(const uint4*)(&Ps[lane][c * 8]);
}

extern "C" void kernel_launch(void* const* d_in, const int* in_sizes, int n_in,
                              void* d_out, int out_size, void* d_ws, size_t ws_size,
                              hipStream_t stream) {
  const void* text = d_in[0];
  const void* media = d_in[1];
  const void* mloc = d_in[2];
  const void* wq  = d_in[3];
  const void* wkv = d_in[4];
  const void* wo  = d_in[5];
  const void* bo  = d_in[6];
  const void* lng = d_in[7];
  const void* lnb = d_in[8];

  char* ws = (char*)d_ws;
  const size_t OFF_FLAG = (size_t)32 << 10;
  const size_t OFF_TN   = (size_t)64 << 10;
  const size_t OFF_WQT  = OFF_TN  + ((size_t)16 << 20) + ((size_t)64 << 10);
  const size_t OFF_WKVT = OFF_WQT + ((size_t)2 << 20);
  const size_t OFF_WOT  = OFF_WKVT + ((size_t)4 << 20);
  const size_t OFF_KV   = OFF_WOT + ((size_t)2 << 20);
  const size_t OFF_MB   = OFF_KV  + ((size_t)8 << 20);
  const size_t OFF_BO   = OFF_MB  + ((size_t)4 << 20);
  const size_t OFF_QB   = OFF_BO  + ((size_t)64 << 10);
  int* tt               = (int*)(ws + 0);
  int* flag             = (int*)(ws + OFF_FLAG);
  unsigned short* tn    = (unsigned short*)(ws + OFF_TN);
  unsigned short* ao    = tn;                               // reuse after q GEMM
  unsigned short* wqt   = (unsigned short*)(ws + OFF_WQT);
  unsigned short* wkvt  = (unsigned short*)(ws + OFF_WKVT);
  unsigned short* wot   = (unsigned short*)(ws + OFF_WOT);
  unsigned short* kvb   = (unsigned short*)(ws + OFF_KV);
  unsigned short* mb    = (unsigned short*)(ws + OFF_MB);
  unsigned short* bob   = (unsigned short*)(ws + OFF_BO);
  unsigned short* qb    = (unsigned short*)(ws + OFF_QB);

  detect_kernel<<<1, 256, 0, stream>>>((const unsigned short*)text, flag);
  times_kernel<<<B_, 256, 0, stream>>>(mloc, tt);
  ln_kernel<<<B_ * N_, 256, 0, stream>>>(text, lng, lnb, tn, flag);
  cast2_kernel<<<2049, 256, 0, stream>>>(media, mb, bo, bob, flag);
  transpose3_kernel<<<dim3(64, 32, 3), dim3(32, 8), 0, stream>>>(wq, wqt, wkv, wkvt, wo, wot, flag);

  // fused q (2048 blocks) + kv (1024 blocks) register-fragment GEMM
  gemm_qkv<<<3072, 64, 0, stream>>>(tn, wqt, qb, mb, wkvt, kvb);
  // attention: 1 wave per (b, 64-row tile, head)
  attn_mfma<<<B_ * (N_/64) * H_, 64, 0, stream>>>(qb, kvb, tt, ao);
  // out = ao @ wo + bo (fp32 out if inputs fp32)
  gemm_out<<<2048, 64, 0, stream>>>(ao, wot, (unsigned short*)d_out, (float*)d_out, bob, flag);
}

// Round 10
// 213.545 us; speedup vs baseline: 1.4508x; 1.4508x over previous
//
#include <hip/hip_runtime.h>
#include <stdint.h>

#define B_ 4
#define N_ 2048
#define T_ 8
#define NL_ 64
#define DIM_ 1024
#define H_ 16
#define HD_ 64
#define TN_ (T_*NL_)   // 512

typedef __bf16 bf16x8 __attribute__((ext_vector_type(8)));
typedef float f32x4 __attribute__((ext_vector_type(4)));

__device__ __forceinline__ float b2f(unsigned short x) {
  union { uint32_t u; float f; } v; v.u = ((uint32_t)x) << 16; return v.f;
}
__device__ __forceinline__ unsigned short f2b(float f) {
  union { float f; uint32_t u; } v; v.f = f;
  uint32_t r = v.u + 0x7FFFu + ((v.u >> 16) & 1u);
  return (unsigned short)(r >> 16);
}

// ---------------- fp32-vs-bf16 storage detection ----------------
__global__ void detect_kernel(const unsigned short* __restrict__ text, int* __restrict__ flag) {
  int t = threadIdx.x;
  int bad = 0;
  #pragma unroll
  for (int i = 0; i < 16; i++) {
    unsigned short w = text[t * 16 + i];
    int e = (w >> 7) & 0xFF;
    if (e != 0 && (e < 90 || e > 150)) bad++;
  }
  __shared__ int red[256];
  red[t] = bad;
  __syncthreads();
  for (int o = 128; o > 0; o >>= 1) { if (t < o) red[t] += red[t + o]; __syncthreads(); }
  if (t == 0) flag[0] = (red[0] > 256) ? 1 : 0;   // 1 = fp32 storage
}

// ---------------- merged cast to bf16: media (2M elems) + bo (1K elems) --------
__global__ void cast2_kernel(const void* __restrict__ media, unsigned short* __restrict__ mb,
                             const void* __restrict__ bo, unsigned short* __restrict__ bob,
                             const int* __restrict__ flag) {
  const int N4M = (B_*T_*NL_*DIM_) / 4;   // 524288
  int i = blockIdx.x * 256 + threadIdx.x;
  bool isf = (*flag != 0);
  if (i < N4M) {
    ushort4 o;
    if (isf) {
      float4 v = ((const float4*)media)[i];
      o.x = f2b(v.x); o.y = f2b(v.y); o.z = f2b(v.z); o.w = f2b(v.w);
    } else {
      o = ((const ushort4*)media)[i];
    }
    ((ushort4*)mb)[i] = o;
  } else {
    int j = i - N4M;
    if (j < DIM_/4) {
      ushort4 o;
      if (isf) {
        float4 v = ((const float4*)bo)[j];
        o.x = f2b(v.x); o.y = f2b(v.y); o.z = f2b(v.z); o.w = f2b(v.w);
      } else {
        o = ((const ushort4*)bo)[j];
      }
      ((ushort4*)bob)[j] = o;
    }
  }
}

// ---------------- text_times: detect storage (bool-bytes vs int32) + block scan ----
__global__ void times_kernel(const void* __restrict__ locs, int* __restrict__ tt) {
  int b = blockIdx.x, t = threadIdx.x;
  const unsigned char* p8 = (const unsigned char*)locs;
  const int* p32 = (const int*)locs;
  __shared__ int red[256];
  int cnt = 0;
  for (int i = t; i < B_*N_; i += 256) cnt += (p8[i] != 0) ? 1 : 0;
  red[t] = cnt;
  __syncthreads();
  for (int off = 128; off > 0; off >>= 1) {
    if (t < off) red[t] += red[t + off];
    __syncthreads();
  }
  int total = red[0];
  __syncthreads();
  bool isb = (total >= 2 * T_);
  int x[8];
  int base = b * N_ + t * 8;
  if (isb) {
    #pragma unroll
    for (int i = 0; i < 8; i++) x[i] = (int)(p8[base + i] != 0);
  } else {
    #pragma unroll
    for (int i = 0; i < 8; i++) x[i] = (int)(p32[base + i] != 0);
  }
  #pragma unroll
  for (int i = 1; i < 8; i++) x[i] += x[i-1];
  int tot = x[7];
  red[t] = tot;
  __syncthreads();
  for (int off = 1; off < 256; off <<= 1) {
    int v = (t >= off) ? red[t - off] : 0;
    __syncthreads();
    red[t] += v;
    __syncthreads();
  }
  int excl = red[t] - tot;
  #pragma unroll
  for (int i = 0; i < 8; i++) tt[base + i] = excl + x[i];
}

// ---------------- LayerNorm (row per block), dtype-flag aware ----------------
__global__ void ln_kernel(const void* __restrict__ x,
                          const void* __restrict__ g,
                          const void* __restrict__ bta,
                          unsigned short* __restrict__ y,
                          const int* __restrict__ flag) {
  int row = blockIdx.x;
  int t = threadIdx.x;
  bool isf = (*flag != 0);
  float f0, f1, f2, f3, g0, g1, g2, g3, c0, c1, c2, c3;
  if (isf) {
    float4 xv = ((const float4*)x)[(size_t)row * (DIM_/4) + t];
    f0 = xv.x; f1 = xv.y; f2 = xv.z; f3 = xv.w;
    float4 gv = ((const float4*)g)[t];
    g0 = gv.x; g1 = gv.y; g2 = gv.z; g3 = gv.w;
    float4 bv = ((const float4*)bta)[t];
    c0 = bv.x; c1 = bv.y; c2 = bv.z; c3 = bv.w;
  } else {
    ushort4 xv = ((const ushort4*)x)[(size_t)row * (DIM_/4) + t];
    f0 = b2f(xv.x); f1 = b2f(xv.y); f2 = b2f(xv.z); f3 = b2f(xv.w);
    ushort4 gv = ((const ushort4*)g)[t];
    g0 = b2f(gv.x); g1 = b2f(gv.y); g2 = b2f(gv.z); g3 = b2f(gv.w);
    ushort4 bv = ((const ushort4*)bta)[t];
    c0 = b2f(bv.x); c1 = b2f(bv.y); c2 = b2f(bv.z); c3 = b2f(bv.w);
  }
  float s  = f0 + f1 + f2 + f3;
  float s2 = f0*f0 + f1*f1 + f2*f2 + f3*f3;
  for (int off = 32; off > 0; off >>= 1) { s += __shfl_xor(s, off); s2 += __shfl_xor(s2, off); }
  __shared__ float sm[8];
  int wave = t >> 6, lane = t & 63;
  if (lane == 0) { sm[wave] = s; sm[wave + 4] = s2; }
  __syncthreads();
  float ts  = sm[0] + sm[1] + sm[2] + sm[3];
  float ts2 = sm[4] + sm[5] + sm[6] + sm[7];
  float mean = ts * (1.0f / DIM_);
  float var  = ts2 * (1.0f / DIM_) - mean * mean;
  float rs = rsqrtf(var + 1e-5f);
  ushort4 o;
  o.x = f2b((f0 - mean) * rs * g0 + c0);
  o.y = f2b((f1 - mean) * rs * g1 + c1);
  o.z = f2b((f2 - mean) * rs * g2 + c2);
  o.w = f2b((f3 - mean) * rs * g3 + c3);
  ((ushort4*)(y + (size_t)row * DIM_))[t] = o;
}

// ---------------- merged transpose+cast of all 3 weights (grid.z selects) ------
__global__ void transpose3_kernel(const void* __restrict__ wq, unsigned short* __restrict__ wqt,
                                  const void* __restrict__ wkv, unsigned short* __restrict__ wkvt,
                                  const void* __restrict__ wo, unsigned short* __restrict__ wot,
                                  const int* __restrict__ flag) {
  const void* src; unsigned short* dst; int C;
  if (blockIdx.z == 0)      { src = wq;  dst = wqt;  C = 1024; }
  else if (blockIdx.z == 1) { src = wkv; dst = wkvt; C = 2048; }
  else                      { src = wo;  dst = wot;  C = 1024; }
  const int R = 1024;
  int bx = blockIdx.x * 32, by = blockIdx.y * 32;
  if (bx >= C) return;
  __shared__ unsigned short tile[32][33];
  int x = threadIdx.x, y = threadIdx.y;
  if (*flag) {
    const float* s = (const float*)src;
    for (int i = y; i < 32; i += 8) tile[i][x] = f2b(s[(size_t)(by + i) * C + bx + x]);
  } else {
    const unsigned short* s = (const unsigned short*)src;
    for (int i = y; i < 32; i += 8) tile[i][x] = s[(size_t)(by + i) * C + bx + x];
  }
  __syncthreads();
  for (int i = y; i < 32; i += 8) dst[(size_t)(bx + i) * R + by + x] = tile[x][i];
}

// ---------------- 128x128 MFMA GEMM core (R5 structure: register-staged LDS) ----
// C[M,N] = A[M,K] @ Bt[N,K]^T (+bias). 256 threads, 4 waves in 2x2 over the tile.
// 1-D m-fastest bid mapping: m = bid % mtiles, n = bid / mtiles. Blocks sharing
// an A-row-tile sit 8 apart -> same XCD (bid%8 round-robin) -> A L2-filled once
// per XCD instead of 8x (R6-R7 FETCH showed 66.6 MB vs 18 ideal).
__device__ __forceinline__ void gemm128_core(const unsigned short* __restrict__ A,
                                             const unsigned short* __restrict__ Bt,
                                             unsigned short* __restrict__ C,
                                             float* __restrict__ Cf,
                                             const unsigned short* __restrict__ bias,
                                             int bid, int mtiles, int M, int N, int K,
                                             bool f32o, int t) {
  __shared__ unsigned short As[128][32];
  __shared__ unsigned short Bs[128][32];
  int m0 = (bid % mtiles) * 128, n0 = (bid / mtiles) * 128;
  int wave = t >> 6, lane = t & 63;
  int wr = wave >> 1, wc = wave & 1;
  f32x4 acc[4][4];
  #pragma unroll
  for (int i = 0; i < 4; i++)
    #pragma unroll
    for (int j = 0; j < 4; j++)
      #pragma unroll
      for (int r = 0; r < 4; r++) acc[i][j][r] = 0.f;
  int lr = lane & 15, lk = (lane >> 4) * 8;
  for (int k0 = 0; k0 < K; k0 += 32) {
    #pragma unroll
    for (int it = 0; it < 2; ++it) {
      int c = t + it * 256;           // 512 chunks of 8 bf16
      int row = c >> 2, kc = (c & 3) * 8;
      *(uint4*)(&As[row][kc]) = *(const uint4*)(&A[(size_t)(m0 + row) * K + k0 + kc]);
      *(uint4*)(&Bs[row][kc]) = *(const uint4*)(&Bt[(size_t)(n0 + row) * K + k0 + kc]);
    }
    __syncthreads();
    bf16x8 af[4], bfr[4];
    #pragma unroll
    for (int i = 0; i < 4; i++) af[i]  = *(const bf16x8*)(&As[wr * 64 + i * 16 + lr][lk]);
    #pragma unroll
    for (int j = 0; j < 4; j++) bfr[j] = *(const bf16x8*)(&Bs[wc * 64 + j * 16 + lr][lk]);
    #pragma unroll
    for (int i = 0; i < 4; i++)
      #pragma unroll
      for (int j = 0; j < 4; j++)
        acc[i][j] = __builtin_amdgcn_mfma_f32_16x16x32_bf16(af[i], bfr[j], acc[i][j], 0, 0, 0);
    __syncthreads();
  }
  int rbase = (lane >> 4) * 4;
  int cbase = lane & 15;
  #pragma unroll
  for (int i = 0; i < 4; i++) {
    #pragma unroll
    for (int j = 0; j < 4; j++) {
      int row = m0 + wr * 64 + i * 16 + rbase;
      int col = n0 + wc * 64 + j * 16 + cbase;
      float bv = bias ? b2f(bias[col]) : 0.f;
      if (f32o) {
        #pragma unroll
        for (int r = 0; r < 4; r++)
          Cf[(size_t)(row + r) * N + col] = acc[i][j][r] + bv;
      } else {
        #pragma unroll
        for (int r = 0; r < 4; r++)
          C[(size_t)(row + r) * N + col] = f2b(acc[i][j][r] + bv);
      }
    }
  }
}

// fused q-GEMM (blocks [0,512): 64 mtiles x 8 ntiles) +
//       kv-GEMM (blocks [512,768): 16 mtiles x 16 ntiles = 256 blocks)
__global__ __launch_bounds__(256) void gemm_qkv(const unsigned short* __restrict__ tn,
                                                const unsigned short* __restrict__ wqt,
                                                unsigned short* __restrict__ qb,
                                                const unsigned short* __restrict__ mb,
                                                const unsigned short* __restrict__ wkvt,
                                                unsigned short* __restrict__ kvb) {
  int bid = blockIdx.x;
  if (bid < 512)
    gemm128_core(tn, wqt, qb, nullptr, nullptr, bid, 64, B_ * N_, DIM_, DIM_, false, threadIdx.x);
  else
    gemm128_core(mb, wkvt, kvb, nullptr, nullptr, bid - 512, 16, B_ * TN_, 2 * DIM_, DIM_, false, threadIdx.x);
}

__global__ __launch_bounds__(256) void gemm_out(const unsigned short* __restrict__ ao,
                                                const unsigned short* __restrict__ wot,
                                                unsigned short* __restrict__ C,
                                                float* __restrict__ Cf,
                                                const unsigned short* __restrict__ bias,
                                                const int* __restrict__ flag) {
  bool f32o = (*flag != 0);
  gemm128_core(ao, wot, C, Cf, bias, blockIdx.x, 64, B_ * N_, DIM_, DIM_, f32o, threadIdx.x);
}

// ---------------- MFMA attention: 1 wave per (b, 64-row tile, head) -------------
__global__ __launch_bounds__(64) void attn_mfma(const unsigned short* __restrict__ q,
                                                const unsigned short* __restrict__ kv,
                                                const int* __restrict__ tt,
                                                unsigned short* __restrict__ ao) {
  __shared__ unsigned short Vt[64][72];   // V^T [d][key]
  __shared__ unsigned short Ps[64][72];   // P [q][key]; reused as O staging
  int bid = blockIdx.x;
  int h  = bid & 15;
  int nt = (bid >> 4) & 31;
  int b  = bid >> 9;
  int bn0 = b * N_ + nt * 64;
  int lane = threadIdx.x & 63;
  int lr = lane & 15;
  int g  = lane >> 4;
  int g8 = g * 8;

  int tv = tt[bn0];             // tile-uniform by mask structure
  float vmul = (tv >= 1 && tv <= T_) ? 1.f : 0.f;
  int tvc = tv < 1 ? 1 : (tv > T_ ? T_ : tv);
  int kvrow0 = b * TN_ + (tvc - 1) * NL_;

  const unsigned short* vbase = kv + (size_t)kvrow0 * (2 * DIM_) + DIM_ + h * HD_;
  #pragma unroll
  for (int d0 = 0; d0 < 64; d0 += 8) {
    uint4 v = *(const uint4*)(vbase + (size_t)lane * (2 * DIM_) + d0);
    Vt[d0 + 0][lane] = (unsigned short)(v.x & 0xffff);
    Vt[d0 + 1][lane] = (unsigned short)(v.x >> 16);
    Vt[d0 + 2][lane] = (unsigned short)(v.y & 0xffff);
    Vt[d0 + 3][lane] = (unsigned short)(v.y >> 16);
    Vt[d0 + 4][lane] = (unsigned short)(v.z & 0xffff);
    Vt[d0 + 5][lane] = (unsigned short)(v.z >> 16);
    Vt[d0 + 6][lane] = (unsigned short)(v.w & 0xffff);
    Vt[d0 + 7][lane] = (unsigned short)(v.w >> 16);
  }

  f32x4 S[4][4];
  #pragma unroll
  for (int i = 0; i < 4; i++)
    #pragma unroll
    for (int j = 0; j < 4; j++)
      #pragma unroll
      for (int r = 0; r < 4; r++) S[i][j][r] = 0.f;
  #pragma unroll
  for (int ks = 0; ks < 2; ks++) {
    bf16x8 aQ[4], bK[4];
    #pragma unroll
    for (int mi = 0; mi < 4; mi++)
      aQ[mi] = *(const bf16x8*)(q + (size_t)(bn0 + mi * 16 + lr) * DIM_ + h * HD_ + ks * 32 + g8);
    #pragma unroll
    for (int ni = 0; ni < 4; ni++)
      bK[ni] = *(const bf16x8*)(kv + (size_t)(kvrow0 + ni * 16 + lr) * (2 * DIM_) + h * HD_ + ks * 32 + g8);
    #pragma unroll
    for (int mi = 0; mi < 4; mi++)
      #pragma unroll
      for (int ni = 0; ni < 4; ni++)
        S[mi][ni] = __builtin_amdgcn_mfma_f32_16x16x32_bf16(aQ[mi], bK[ni], S[mi][ni], 0, 0, 0);
  }

  #pragma unroll
  for (int mi = 0; mi < 4; mi++) {
    #pragma unroll
    for (int r = 0; r < 4; r++) {
      float mx = fmaxf(fmaxf(S[mi][0][r], S[mi][1][r]), fmaxf(S[mi][2][r], S[mi][3][r]));
      mx = fmaxf(mx, __shfl_xor(mx, 1));
      mx = fmaxf(mx, __shfl_xor(mx, 2));
      mx = fmaxf(mx, __shfl_xor(mx, 4));
      mx = fmaxf(mx, __shfl_xor(mx, 8));
      float e0 = __expf(S[mi][0][r] - mx);
      float e1 = __expf(S[mi][1][r] - mx);
      float e2 = __expf(S[mi][2][r] - mx);
      float e3 = __expf(S[mi][3][r] - mx);
      float sum = e0 + e1 + e2 + e3;
      sum += __shfl_xor(sum, 1);
      sum += __shfl_xor(sum, 2);
      sum += __shfl_xor(sum, 4);
      sum += __shfl_xor(sum, 8);
      float inv = 1.f / sum;
      int qrow = mi * 16 + g * 4 + r;
      Ps[qrow][ 0 + lr] = f2b(e0 * inv);
      Ps[qrow][16 + lr] = f2b(e1 * inv);
      Ps[qrow][32 + lr] = f2b(e2 * inv);
      Ps[qrow][48 + lr] = f2b(e3 * inv);
    }
  }
  __syncthreads();

  f32x4 O[4][4];
  #pragma unroll
  for (int i = 0; i < 4; i++)
    #pragma unroll
    for (int j = 0; j < 4; j++)
      #pragma unroll
      for (int r = 0; r < 4; r++) O[i][j][r] = 0.f;
  #pragma unroll
  for (int ks = 0; ks < 2; ks++) {
    bf16x8 aP[4], bV[4];
    #pragma unroll
    for (int mi = 0; mi < 4; mi++)
      aP[mi] = *(const bf16x8*)(&Ps[mi * 16 + lr][ks * 32 + g8]);
    #pragma unroll
    for (int ni = 0; ni < 4; ni++)
      bV[ni] = *(const bf16x8*)(&Vt[ni * 16 + lr][ks * 32 + g8]);
    #pragma unroll
    for (int mi = 0; mi < 4; mi++)
      #pragma unroll
      for (int ni = 0; ni < 4; ni++)
        O[mi][ni] = __builtin_amdgcn_mfma_f32_16x16x32_bf16(aP[mi], bV[ni], O[mi][ni], 0, 0, 0);
  }
  __syncthreads();

  #pragma unroll
  for (int mi = 0; mi < 4; mi++)
    #pragma unroll
    for (int ni = 0; ni < 4; ni++)
      #pragma unroll
      for (int r = 0; r < 4; r++)
        Ps[mi * 16 + g * 4 + r][ni * 16 + lr] = f2b(O[mi][ni][r] * vmul);
  __syncthreads();
  uint4* dst = (uint4*)(ao + (size_t)(bn0 + lane) * DIM_ + h * HD_);
  #pragma unroll
  for (int c = 0; c < 8; c++)
    dst[c] = *(const uint4*)(&Ps[lane][c * 8]);
}

extern "C" void kernel_launch(void* const* d_in, const int* in_sizes, int n_in,
                              void* d_out, int out_size, void* d_ws, size_t ws_size,
                              hipStream_t stream) {
  const void* text = d_in[0];
  const void* media = d_in[1];
  const void* mloc = d_in[2];
  const void* wq  = d_in[3];
  const void* wkv = d_in[4];
  const void* wo  = d_in[5];
  const void* bo  = d_in[6];
  const void* lng = d_in[7];
  const void* lnb = d_in[8];

  char* ws = (char*)d_ws;
  const size_t OFF_FLAG = (size_t)32 << 10;
  const size_t OFF_TN   = (size_t)64 << 10;
  const size_t OFF_WQT  = OFF_TN  + ((size_t)16 << 20) + ((size_t)64 << 10);
  const size_t OFF_WKVT = OFF_WQT + ((size_t)2 << 20);
  const size_t OFF_WOT  = OFF_WKVT + ((size_t)4 << 20);
  const size_t OFF_KV   = OFF_WOT + ((size_t)2 << 20);
  const size_t OFF_MB   = OFF_KV  + ((size_t)8 << 20);
  const size_t OFF_BO   = OFF_MB  + ((size_t)4 << 20);
  const size_t OFF_QB   = OFF_BO  + ((size_t)64 << 10);
  int* tt               = (int*)(ws + 0);
  int* flag             = (int*)(ws + OFF_FLAG);
  unsigned short* tn    = (unsigned short*)(ws + OFF_TN);
  unsigned short* ao    = tn;                               // reuse after q GEMM
  unsigned short* wqt   = (unsigned short*)(ws + OFF_WQT);
  unsigned short* wkvt  = (unsigned short*)(ws + OFF_WKVT);
  unsigned short* wot   = (unsigned short*)(ws + OFF_WOT);
  unsigned short* kvb   = (unsigned short*)(ws + OFF_KV);
  unsigned short* mb    = (unsigned short*)(ws + OFF_MB);
  unsigned short* bob   = (unsigned short*)(ws + OFF_BO);
  unsigned short* qb    = (unsigned short*)(ws + OFF_QB);

  detect_kernel<<<1, 256, 0, stream>>>((const unsigned short*)text, flag);
  times_kernel<<<B_, 256, 0, stream>>>(mloc, tt);
  ln_kernel<<<B_ * N_, 256, 0, stream>>>(text, lng, lnb, tn, flag);
  cast2_kernel<<<2049, 256, 0, stream>>>(media, mb, bo, bob, flag);
  transpose3_kernel<<<dim3(64, 32, 3), dim3(32, 8), 0, stream>>>(wq, wqt, wkv, wkvt, wo, wot, flag);

  // fused q (512 blocks, m-fastest) + kv (256 blocks) 128^2 register-staged GEMM
  gemm_qkv<<<768, 256, 0, stream>>>(tn, wqt, qb, mb, wkvt, kvb);
  // attention: 1 wave per (b, 64-row tile, head)
  attn_mfma<<<B_ * (N_/64) * H_, 64, 0, stream>>>(qb, kvb, tt, ao);
  // out = ao @ wo + bo (fp32 out if inputs fp32)
  gemm_out<<<512, 256, 0, stream>>>(ao, wot, (unsigned short*)d_out, (float*)d_out, bob, flag);
}